// Round 6
// baseline (125.758 us; speedup 1.0000x reference)
//
#include <hip/hip_runtime.h>
#include <math.h>

namespace {
constexpr int kB = 4;
constexpr int kS = 4096;
constexpr int kH = 4096;
constexpr int kE = 16;
constexpr int kTokens = kB * kS;            // 16384
constexpr int kT = 8;                       // tokens per wave tile
constexpr int kEW = 8;                      // experts per wave tile (e-split 2)
constexpr int kThreads = 256;               // 4 waves: 2 token-groups x 2 e-halves
constexpr int kTokBlk = 16;                 // tokens per block
constexpr int kGrid = kTokens / kTokBlk;    // 1024 -> whole grid resident
constexpr int kChunk = 256;                 // floats of H per j-iter (float4/lane)
constexpr int kNC = kH / kChunk;            // 16
}  // namespace

// Pure-streaming gate GEMM, register-tiled 8 tok x 8 exp per wave.
// Load order per j: all 8 x-float4 (HBM, longest latency) first, then W in two
// 4-row phases (L2) — vmcnt FIFO means the first FMA's wait drains x exactly
// once, and phase-B W loads wait only ~L2 latency. No LDS in the main loop.
__global__ __launch_bounds__(kThreads) void router_main(
    const float* __restrict__ x, const float* __restrict__ W,
    float* __restrict__ out_probs,   // [kTokens][2]
    float* __restrict__ out_idx,     // [kTokens][2] (indices as float)
    float* __restrict__ gpart) {     // [kGrid][32]: cnt[16], psum[16] per block
  __shared__ float s_logit[kTokBlk][kE];
  __shared__ float s_cnt[kE];
  __shared__ float s_psum[kE];

  const int tid = threadIdx.x;
  const int wave = tid >> 6;
  const int lane = tid & 63;
  const int tg = wave >> 1;                 // token group: 0 or 1 (8 tokens each)
  const int eo = (wave & 1) * kEW;          // expert offset: 0 or 8
  const int tokBase = blockIdx.x * kTokBlk;
  const int tok0 = tokBase + tg * kT;

  if (tid < kE) { s_cnt[tid] = 0.f; s_psum[tid] = 0.f; }

  float acc[kT][kEW];
#pragma unroll
  for (int t = 0; t < kT; ++t)
#pragma unroll
    for (int e = 0; e < kEW; ++e) acc[t][e] = 0.f;

  const int lo = lane * 4;                  // per-lane float offset (v_off)

#pragma unroll 1
  for (int j = 0; j < kNC; ++j) {
    const int off = j * kChunk;             // uniform -> SGPR bases per row

    // 1) x: 8 coalesced float4 loads, issued first (HBM stream).
    float4 xv[kT];
#pragma unroll
    for (int t = 0; t < kT; ++t)
      xv[t] = *reinterpret_cast<const float4*>(
          x + (size_t)(tok0 + t) * kH + off + lo);

    // 2) W phase A: rows eo..eo+3, then FMA block A.
    float4 wv[4];
#pragma unroll
    for (int e = 0; e < 4; ++e)
      wv[e] = *reinterpret_cast<const float4*>(
          W + (size_t)(eo + e) * kH + off + lo);
#pragma unroll
    for (int e = 0; e < 4; ++e)
#pragma unroll
      for (int t = 0; t < kT; ++t) {
        acc[t][e] = fmaf(xv[t].x, wv[e].x, acc[t][e]);
        acc[t][e] = fmaf(xv[t].y, wv[e].y, acc[t][e]);
        acc[t][e] = fmaf(xv[t].z, wv[e].z, acc[t][e]);
        acc[t][e] = fmaf(xv[t].w, wv[e].w, acc[t][e]);
      }

    // 3) W phase B: rows eo+4..eo+7 (reuses wv regs), FMA block B.
#pragma unroll
    for (int e = 0; e < 4; ++e)
      wv[e] = *reinterpret_cast<const float4*>(
          W + (size_t)(eo + 4 + e) * kH + off + lo);
#pragma unroll
    for (int e = 0; e < 4; ++e)
#pragma unroll
      for (int t = 0; t < kT; ++t) {
        acc[t][4 + e] = fmaf(xv[t].x, wv[e].x, acc[t][4 + e]);
        acc[t][4 + e] = fmaf(xv[t].y, wv[e].y, acc[t][4 + e]);
        acc[t][4 + e] = fmaf(xv[t].z, wv[e].z, acc[t][4 + e]);
        acc[t][4 + e] = fmaf(xv[t].w, wv[e].w, acc[t][4 + e]);
      }
  }

  // Butterfly: every lane ends with full-H sums for its 8x8 tile.
#pragma unroll
  for (int off = 1; off < 64; off <<= 1) {
#pragma unroll
    for (int t = 0; t < kT; ++t)
#pragma unroll
      for (int e = 0; e < kEW; ++e)
        acc[t][e] += __shfl_xor(acc[t][e], off, 64);
  }

  // Lanes 0..7 of each wave publish their token's 8-expert slice.
  if (lane < kT) {
    const int r = tg * kT + lane;
#pragma unroll
    for (int e = 0; e < kEW; ++e) s_logit[r][eo + e] = acc[lane][e];
  }
  __syncthreads();

  // Wave 0, lanes 0..15: one token each — softmax, top-2, outputs, aux partials.
  if (wave == 0 && lane < kTokBlk) {
    const int tok = tokBase + lane;
    float l[kE];
#pragma unroll
    for (int e = 0; e < kE; ++e) l[e] = s_logit[lane][e];

    float m = l[0];
#pragma unroll
    for (int e = 1; e < kE; ++e) m = fmaxf(m, l[e]);
    float p[kE];
    float s = 0.f;
#pragma unroll
    for (int e = 0; e < kE; ++e) { p[e] = __expf(l[e] - m); s += p[e]; }
    const float inv = 1.f / s;
#pragma unroll
    for (int e = 0; e < kE; ++e) p[e] *= inv;

    // top-2 on probs (reference: top_k AFTER softmax; ties -> lowest index)
    int i1 = 0;
    float v1 = p[0];
#pragma unroll
    for (int e = 1; e < kE; ++e)
      if (p[e] > v1) { v1 = p[e]; i1 = e; }
    int i2 = (i1 == 0) ? 1 : 0;
    float v2 = p[i2];
#pragma unroll
    for (int e = 0; e < kE; ++e) {
      if (e == i1) continue;
      if (p[e] > v2) { v2 = p[e]; i2 = e; }
    }

    const float ns = 1.f / (v1 + v2);
    out_probs[tok * 2 + 0] = v1 * ns;
    out_probs[tok * 2 + 1] = v2 * ns;
    out_idx[tok * 2 + 0] = (float)i1;
    out_idx[tok * 2 + 1] = (float)i2;

#pragma unroll
    for (int e = 0; e < kE; ++e) atomicAdd(&s_psum[e], p[e]);
    atomicAdd(&s_cnt[i1], 1.f);
    atomicAdd(&s_cnt[i2], 1.f);
  }
  __syncthreads();
  // Per-block partials (coalesced store); reduced by aux_finish.
  if (tid < 2 * kE)
    gpart[(size_t)blockIdx.x * 2 * kE + tid] =
        (tid < kE) ? s_cnt[tid] : s_psum[tid - kE];
}

// Reduce per-block partials; aux = E * sum_e (cnt_e/B) * (psum_e/(B*S)).
__global__ __launch_bounds__(1024) void aux_finish(
    const float* __restrict__ gpart, float* __restrict__ out_aux) {
  __shared__ float s_red[32][32];
  __shared__ float s_final[32];
  const int tid = threadIdx.x;
  const int c = tid & 31;       // column: 0-15 cnt, 16-31 psum
  const int r0 = tid >> 5;      // row-slice 0..31
  float s = 0.f;
  for (int k = 0; k < kGrid / 32; ++k)
    s += gpart[(size_t)(r0 * (kGrid / 32) + k) * 32 + c];
  s_red[r0][c] = s;
  __syncthreads();
  if (tid < 32) {
    float t = 0.f;
    for (int r = 0; r < 32; ++r) t += s_red[r][tid];
    s_final[tid] = t;
  }
  __syncthreads();
  if (tid == 0) {
    double acc = 0.0;
    for (int e = 0; e < kE; ++e)
      acc += (double)s_final[e] * (double)s_final[kE + e];
    out_aux[0] = (float)(acc * (double)kE / ((double)kB * (double)kB * (double)kS));
  }
}

extern "C" void kernel_launch(void* const* d_in, const int* in_sizes, int n_in,
                              void* d_out, int out_size, void* d_ws, size_t ws_size,
                              hipStream_t stream) {
  const float* x = (const float*)d_in[0];   // [B,S,H] f32
  const float* W = (const float*)d_in[1];   // [E,H]   f32
  float* out = (float*)d_out;               // [32768 probs][32768 idx][1 aux]
  float* gpart = (float*)d_ws;              // [kGrid][32], fully overwritten

  router_main<<<kGrid, kThreads, 0, stream>>>(
      x, W, out, out + 2 * kTokens, gpart);
  aux_finish<<<1, 1024, 0, stream>>>(gpart, out + 4 * kTokens);
}

// Round 7
// 119.177 us; speedup vs baseline: 1.0552x; 1.0552x over previous
//
#include <hip/hip_runtime.h>
#include <math.h>

namespace {
constexpr int kB = 4;
constexpr int kS = 4096;
constexpr int kH = 4096;
constexpr int kE = 16;
constexpr int kTokens = kB * kS;            // 16384
constexpr int kT = 4;                       // tokens per wave (all 16 experts)
constexpr int kWaves = 4;
constexpr int kThreads = 64 * kWaves;       // 256
constexpr int kTokBlk = kT * kWaves;        // 16 tokens per block
constexpr int kGrid = kTokens / kTokBlk;    // 1024 -> whole grid resident
constexpr int kChunk = 128;                 // floats of H per pipeline step (512 B/row)
constexpr int kNC = kH / kChunk;            // 32
constexpr int kRing = 4;                    // W LDS ring; depth-2 prefetch
}  // namespace

__device__ __forceinline__ void gload_lds16(const float* src_lane, float* lds_base) {
  // wave-uniform LDS base; HW adds lane*16. Linear dest + per-lane global src.
  __builtin_amdgcn_global_load_lds(
      (const __attribute__((address_space(1))) void*)src_lane,
      (__attribute__((address_space(3))) void*)lds_base, 16, 0, 0);
}

// x streams HBM->registers (read ONCE: each wave owns all 16 experts of its 4
// tokens). W staged once per block into a 4-deep LDS ring; counted vmcnt(12) +
// single raw s_barrier per chunk keeps 2 chunks of x+W in flight at all times.
__global__ __launch_bounds__(kThreads) void router_main(
    const float* __restrict__ x, const float* __restrict__ W,
    float* __restrict__ out_probs,   // [kTokens][2]
    float* __restrict__ out_idx,     // [kTokens][2] (indices as float)
    float* __restrict__ gpart) {     // transposed [32][kGrid]
  __shared__ float s_w[kRing][kE][kChunk];   // 32 KB
  __shared__ float s_cnt[kE];
  __shared__ float s_psum[kE];

  const int tid = threadIdx.x;
  const int wave = tid >> 6;
  const int lane = tid & 63;
  const int tokBase = blockIdx.x * kTokBlk;
  const int tok0 = tokBase + wave * kT;

  float acc[kT][kE];
#pragma unroll
  for (int t = 0; t < kT; ++t)
#pragma unroll
    for (int e = 0; e < kE; ++e) acc[t][e] = 0.f;

  // Per chunk, each wave stages 4 of the 16 W rows: 2 gload_lds of 1 KB, each
  // covering 2 contiguous 512 B rows (lanes 0-31 -> row r, 32-63 -> row r+1).
  const int wrow = 4 * wave + (lane >> 5);
  const int wcol = (lane & 31) * 4;
  auto stage = [&](int j) {
    const int buf = j & (kRing - 1);
    gload_lds16(W + (size_t)wrow * kH + j * kChunk + wcol, &s_w[buf][4 * wave][0]);
    gload_lds16(W + (size_t)(wrow + 2) * kH + j * kChunk + wcol,
                &s_w[buf][4 * wave + 2][0]);
  };
  auto issue_x = [&](int j, float2 (&xv)[kT]) {
#pragma unroll
    for (int t = 0; t < kT; ++t)
      xv[t] = *reinterpret_cast<const float2*>(
          x + (size_t)(tok0 + t) * kH + j * kChunk + lane * 2);
  };
  auto compute = [&](int j, const float2 (&xv)[kT]) {
    const float* wb = &s_w[j & (kRing - 1)][0][0];
#pragma unroll
    for (int e = 0; e < kE; ++e) {
      const float2 wv =
          *reinterpret_cast<const float2*>(wb + e * kChunk + lane * 2);
#pragma unroll
      for (int t = 0; t < kT; ++t) {
        acc[t][e] = fmaf(xv[t].x, wv.x, acc[t][e]);
        acc[t][e] = fmaf(xv[t].y, wv.y, acc[t][e]);
      }
    }
  };

  float2 xv0[kT], xv1[kT], xv2[kT];

  // Prologue: chunks 0 and 1 in flight (12 VMEM ops/wave: 2 stage + 4 x each).
  stage(0);
  issue_x(0, xv0);
  stage(1);
  issue_x(1, xv1);

  // Main body: at iter j, issue chunk j+2, wait own chunk-j ops (12 newer stay
  // in flight), barrier (all waves' stage(j) landed), compute chunk j.
  auto body = [&](int j, float2 (&use)[kT], float2 (&iss)[kT]) {
    stage(j + 2);
    issue_x(j + 2, iss);
    asm volatile("s_waitcnt vmcnt(12)" ::: "memory");
    __builtin_amdgcn_s_barrier();
    asm volatile("" ::: "memory");
    compute(j, use);
    asm volatile("" ::: "memory");
  };

#pragma unroll 1
  for (int jj = 0; jj < kNC - 2; jj += 3) {   // 30 iters, xv ring rotates by 3
    body(jj + 0, xv0, xv2);
    body(jj + 1, xv1, xv0);
    body(jj + 2, xv2, xv1);
  }
  // Tails: j = 30 (uses xv0), j = 31 (uses xv1); no more issues.
  asm volatile("s_waitcnt vmcnt(6)" ::: "memory");
  __builtin_amdgcn_s_barrier();
  asm volatile("" ::: "memory");
  compute(kNC - 2, xv0);
  asm volatile("s_waitcnt vmcnt(0)" ::: "memory");
  __builtin_amdgcn_s_barrier();
  asm volatile("" ::: "memory");
  compute(kNC - 1, xv1);

  // Butterfly: every lane ends with full-H sums for the wave's 4x16 tile.
#pragma unroll
  for (int off = 1; off < 64; off <<= 1) {
#pragma unroll
    for (int t = 0; t < kT; ++t)
#pragma unroll
      for (int e = 0; e < kE; ++e)
        acc[t][e] += __shfl_xor(acc[t][e], off, 64);
  }

  if (tid < kE) { s_cnt[tid] = 0.f; s_psum[tid] = 0.f; }
  __syncthreads();

  // Lanes 0..3 of each wave: one token each — softmax, top-2, outputs, partials.
  if (lane < kT) {
    const int tok = tok0 + lane;
    float l[kE];
#pragma unroll
    for (int e = 0; e < kE; ++e) l[e] = acc[lane][e];

    float m = l[0];
#pragma unroll
    for (int e = 1; e < kE; ++e) m = fmaxf(m, l[e]);
    float p[kE];
    float s = 0.f;
#pragma unroll
    for (int e = 0; e < kE; ++e) { p[e] = __expf(l[e] - m); s += p[e]; }
    const float inv = 1.f / s;
#pragma unroll
    for (int e = 0; e < kE; ++e) p[e] *= inv;

    // top-2 on probs (reference: top_k AFTER softmax; ties -> lowest index)
    int i1 = 0;
    float v1 = p[0];
#pragma unroll
    for (int e = 1; e < kE; ++e)
      if (p[e] > v1) { v1 = p[e]; i1 = e; }
    int i2 = (i1 == 0) ? 1 : 0;
    float v2 = p[i2];
#pragma unroll
    for (int e = 0; e < kE; ++e) {
      if (e == i1) continue;
      if (p[e] > v2) { v2 = p[e]; i2 = e; }
    }

    const float ns = 1.f / (v1 + v2);
    out_probs[tok * 2 + 0] = v1 * ns;
    out_probs[tok * 2 + 1] = v2 * ns;
    out_idx[tok * 2 + 0] = (float)i1;
    out_idx[tok * 2 + 1] = (float)i2;

#pragma unroll
    for (int e = 0; e < kE; ++e) atomicAdd(&s_psum[e], p[e]);
    atomicAdd(&s_cnt[i1], 1.f);
    atomicAdd(&s_cnt[i2], 1.f);
  }
  __syncthreads();
  // Transposed partials: column-major so aux_finish reads coalesce.
  if (tid < 2 * kE)
    gpart[(size_t)tid * kGrid + blockIdx.x] =
        (tid < kE) ? s_cnt[tid] : s_psum[tid - kE];
}

// Reduce per-block partials; aux = E * sum_e (cnt_e/B) * (psum_e/(B*S)).
__global__ __launch_bounds__(1024) void aux_finish(
    const float* __restrict__ gpart, float* __restrict__ out_aux) {
  __shared__ float s_final[2 * kE];
  const int tid = threadIdx.x;
  const int c = tid >> 5;       // 0..31: which partial column
  const int k = tid & 31;
  float s = 0.f;
  for (int i = 0; i < kGrid / 32; ++i)
    s += gpart[(size_t)c * kGrid + i * 32 + k];   // coalesced per 32-group
#pragma unroll
  for (int off = 1; off < 32; off <<= 1) s += __shfl_xor(s, off, 32);
  if (k == 0) s_final[c] = s;
  __syncthreads();
  if (tid == 0) {
    double acc = 0.0;
    for (int e = 0; e < kE; ++e)
      acc += (double)s_final[e] * (double)s_final[kE + e];
    out_aux[0] = (float)(acc * (double)kE / ((double)kB * (double)kB * (double)kS));
  }
}

extern "C" void kernel_launch(void* const* d_in, const int* in_sizes, int n_in,
                              void* d_out, int out_size, void* d_ws, size_t ws_size,
                              hipStream_t stream) {
  const float* x = (const float*)d_in[0];   // [B,S,H] f32
  const float* W = (const float*)d_in[1];   // [E,H]   f32
  float* out = (float*)d_out;               // [32768 probs][32768 idx][1 aux]
  float* gpart = (float*)d_ws;              // [32][kGrid], fully overwritten

  router_main<<<kGrid, kThreads, 0, stream>>>(
      x, W, out, out + 2 * kTokens, gpart);
  aux_finish<<<1, 1024, 0, stream>>>(gpart, out + 4 * kTokens);
}

// Round 8
// 104.509 us; speedup vs baseline: 1.2033x; 1.1404x over previous
//
#include <hip/hip_runtime.h>
#include <math.h>

namespace {
constexpr int kB = 4;
constexpr int kS = 4096;
constexpr int kH = 4096;
constexpr int kE = 16;
constexpr int kTokens = kB * kS;            // 16384
constexpr int kT = 4;                       // tokens per wave tile
constexpr int kEW = 8;                      // experts per wave tile (e-split 2)
constexpr int kThreads = 256;               // 4 waves: 2 token-groups x 2 e-halves
constexpr int kTokBlk = 8;                  // tokens per block
constexpr int kGrid = kTokens / kTokBlk;    // 2048
constexpr int kChunk = 256;                 // floats of H per j-iter (float4/lane)
constexpr int kNC = kH / kChunk;            // 16
}  // namespace

// Pure-streaming gate GEMM (no LDS / no barriers in the main loop), with a
// FIFO-correct software pipeline: W(j+1) is always issued BEFORE x(j+2), so the
// steady-state `s_waitcnt vmcnt(4)` drains exactly {x(j+1), W(j+1)} while the
// x(j+2) prefetch stays in flight across the whole next iteration (~2 compute
// phases ~ HBM latency). Each wave keeps ~12KB outstanding at all times.
__global__ __launch_bounds__(kThreads) void router_main(
    const float* __restrict__ x, const float* __restrict__ W,
    float* __restrict__ out_probs,   // [kTokens][2]
    float* __restrict__ out_idx,     // [kTokens][2] (indices as float)
    float* __restrict__ gpart) {     // [kGrid][32]: cnt[16], psum[16] per block
  __shared__ float s_logit[kTokBlk][kE];
  __shared__ float s_cnt[kE];
  __shared__ float s_psum[kE];

  const int tid = threadIdx.x;
  const int wave = tid >> 6;
  const int lane = tid & 63;
  const int tg = wave >> 1;                 // token group: 0 or 1
  const int eo = (wave & 1) * kEW;          // expert offset: 0 or 8
  const int tokBase = blockIdx.x * kTokBlk;
  const int tok0 = tokBase + tg * kT;

  if (tid < kE) { s_cnt[tid] = 0.f; s_psum[tid] = 0.f; }

  const float* xb = x + (size_t)tok0 * kH + lane * 4;
  const float* wb = W + (size_t)eo * kH + lane * 4;

  float acc[kT][kEW];
#pragma unroll
  for (int t = 0; t < kT; ++t)
#pragma unroll
    for (int e = 0; e < kEW; ++e) acc[t][e] = 0.f;

  float4 xv0[kT], xv1[kT], xv2[kT];
  float4 wvA[4], wvB[4];

  auto issue_x = [&](int j, float4 (&xv)[kT]) {
    const size_t off = (size_t)j * kChunk;
#pragma unroll
    for (int t = 0; t < kT; ++t)
      xv[t] = *reinterpret_cast<const float4*>(xb + (size_t)t * kH + off);
  };
  auto issue_wA = [&](int j) {
    const size_t off = (size_t)j * kChunk;
#pragma unroll
    for (int e = 0; e < 4; ++e)
      wvA[e] = *reinterpret_cast<const float4*>(wb + (size_t)e * kH + off);
  };
  auto issue_wB = [&](int j) {
    const size_t off = (size_t)j * kChunk;
#pragma unroll
    for (int e = 0; e < 4; ++e)
      wvB[e] = *reinterpret_cast<const float4*>(wb + (size_t)(4 + e) * kH + off);
  };

  // Prologue: W(0), x(0), x(1) in issue order; wait leaves x(1) in flight.
  issue_wA(0);
  issue_wB(0);
  asm volatile("" ::: "memory");
  issue_x(0, xv0);
  asm volatile("" ::: "memory");
  issue_x(1, xv1);
  asm volatile("s_waitcnt vmcnt(4)" ::: "memory");   // W(0)+x(0) done

  // Body for iteration j: cur = xv[j%3], nxt2 = xv[(j+2)%3].
  auto body = [&](int j, const float4 (&cur)[kT], float4 (&nxt2)[kT]) {
    // compute half A (experts eo..eo+3) from wv_A, then reuse wv_A for j+1
#pragma unroll
    for (int e = 0; e < 4; ++e)
#pragma unroll
      for (int t = 0; t < kT; ++t) {
        acc[t][e] = fmaf(cur[t].x, wvA[e].x, acc[t][e]);
        acc[t][e] = fmaf(cur[t].y, wvA[e].y, acc[t][e]);
        acc[t][e] = fmaf(cur[t].z, wvA[e].z, acc[t][e]);
        acc[t][e] = fmaf(cur[t].w, wvA[e].w, acc[t][e]);
      }
    if (j + 1 < kNC) issue_wA(j + 1);
    asm volatile("" ::: "memory");
    // compute half B (experts eo+4..eo+7) from wv_B, then reuse wv_B for j+1
#pragma unroll
    for (int e = 0; e < 4; ++e)
#pragma unroll
      for (int t = 0; t < kT; ++t) {
        acc[t][4 + e] = fmaf(cur[t].x, wvB[e].x, acc[t][4 + e]);
        acc[t][4 + e] = fmaf(cur[t].y, wvB[e].y, acc[t][4 + e]);
        acc[t][4 + e] = fmaf(cur[t].z, wvB[e].z, acc[t][4 + e]);
        acc[t][4 + e] = fmaf(cur[t].w, wvB[e].w, acc[t][4 + e]);
      }
    if (j + 1 < kNC) issue_wB(j + 1);
    asm volatile("" ::: "memory");
    if (j + 2 < kNC) {
      issue_x(j + 2, nxt2);                      // issued AFTER W(j+1): FIFO ok
      asm volatile("s_waitcnt vmcnt(4)" ::: "memory");  // leave x(j+2) in flight
    } else if (j + 1 < kNC) {
      asm volatile("s_waitcnt vmcnt(0)" ::: "memory");  // tail: drain all
    }
  };

#pragma unroll 1
  for (int jj = 0; jj < kNC - 1; jj += 3) {   // j = 0..14 in 5 groups of 3
    body(jj + 0, xv0, xv2);
    body(jj + 1, xv1, xv0);
    body(jj + 2, xv2, xv1);
  }
  body(kNC - 1, xv0, xv2);                    // j = 15 (15%3==0 -> xv0)

  // Butterfly: every lane ends with full-H sums for its 4x8 tile.
#pragma unroll
  for (int off = 1; off < 64; off <<= 1) {
#pragma unroll
    for (int t = 0; t < kT; ++t)
#pragma unroll
      for (int e = 0; e < kEW; ++e)
        acc[t][e] += __shfl_xor(acc[t][e], off, 64);
  }

  // Lanes 0..3 of each wave publish their token's 8-expert slice.
  if (lane < kT) {
    const int r = tg * kT + lane;
#pragma unroll
    for (int e = 0; e < kEW; ++e) s_logit[r][eo + e] = acc[lane][e];
  }
  __syncthreads();

  // Wave 0, lanes 0..7: one token each — softmax, top-2, outputs, aux partials.
  if (wave == 0 && lane < kTokBlk) {
    const int tok = tokBase + lane;
    float l[kE];
#pragma unroll
    for (int e = 0; e < kE; ++e) l[e] = s_logit[lane][e];

    float m = l[0];
#pragma unroll
    for (int e = 1; e < kE; ++e) m = fmaxf(m, l[e]);
    float p[kE];
    float s = 0.f;
#pragma unroll
    for (int e = 0; e < kE; ++e) { p[e] = __expf(l[e] - m); s += p[e]; }
    const float inv = 1.f / s;
#pragma unroll
    for (int e = 0; e < kE; ++e) p[e] *= inv;

    // top-2 on probs (reference: top_k AFTER softmax; ties -> lowest index)
    int i1 = 0;
    float v1 = p[0];
#pragma unroll
    for (int e = 1; e < kE; ++e)
      if (p[e] > v1) { v1 = p[e]; i1 = e; }
    int i2 = (i1 == 0) ? 1 : 0;
    float v2 = p[i2];
#pragma unroll
    for (int e = 0; e < kE; ++e) {
      if (e == i1) continue;
      if (p[e] > v2) { v2 = p[e]; i2 = e; }
    }

    const float ns = 1.f / (v1 + v2);
    out_probs[tok * 2 + 0] = v1 * ns;
    out_probs[tok * 2 + 1] = v2 * ns;
    out_idx[tok * 2 + 0] = (float)i1;
    out_idx[tok * 2 + 1] = (float)i2;

#pragma unroll
    for (int e = 0; e < kE; ++e) atomicAdd(&s_psum[e], p[e]);
    atomicAdd(&s_cnt[i1], 1.f);
    atomicAdd(&s_cnt[i2], 1.f);
  }
  __syncthreads();
  // Per-block partials (coalesced store); reduced by aux_finish.
  if (tid < 2 * kE)
    gpart[(size_t)blockIdx.x * 2 * kE + tid] =
        (tid < kE) ? s_cnt[tid] : s_psum[tid - kE];
}

// Reduce per-block partials; aux = E * sum_e (cnt_e/B) * (psum_e/(B*S)).
__global__ __launch_bounds__(1024) void aux_finish(
    const float* __restrict__ gpart, float* __restrict__ out_aux) {
  __shared__ float s_red[32][32];
  __shared__ float s_final[32];
  const int tid = threadIdx.x;
  const int c = tid & 31;       // column: 0-15 cnt, 16-31 psum
  const int r0 = tid >> 5;      // row-slice 0..31
  float s = 0.f;
  for (int k = 0; k < kGrid / 32; ++k)
    s += gpart[(size_t)(r0 * (kGrid / 32) + k) * 32 + c];
  s_red[r0][c] = s;
  __syncthreads();
  if (tid < 32) {
    float t = 0.f;
    for (int r = 0; r < 32; ++r) t += s_red[r][tid];
    s_final[tid] = t;
  }
  __syncthreads();
  if (tid == 0) {
    double acc = 0.0;
    for (int e = 0; e < kE; ++e)
      acc += (double)s_final[e] * (double)s_final[kE + e];
    out_aux[0] = (float)(acc * (double)kE / ((double)kB * (double)kB * (double)kS));
  }
}

extern "C" void kernel_launch(void* const* d_in, const int* in_sizes, int n_in,
                              void* d_out, int out_size, void* d_ws, size_t ws_size,
                              hipStream_t stream) {
  const float* x = (const float*)d_in[0];   // [B,S,H] f32
  const float* W = (const float*)d_in[1];   // [E,H]   f32
  float* out = (float*)d_out;               // [32768 probs][32768 idx][1 aux]
  float* gpart = (float*)d_ws;              // [kGrid][32], fully overwritten

  router_main<<<kGrid, kThreads, 0, stream>>>(
      x, W, out, out + 2 * kTokens, gpart);
  aux_finish<<<1, 1024, 0, stream>>>(gpart, out + 4 * kTokens);
}